// Round 7
// baseline (4607.453 us; speedup 1.0000x reference)
//
#include <hip/hip_runtime.h>
#include <hip/hip_bf16.h>
#include <math.h>

typedef __attribute__((ext_vector_type(8))) short bf16x8;
typedef __attribute__((ext_vector_type(4))) float f32x4;
typedef __attribute__((ext_vector_type(4))) unsigned short u16x4;

#define B_   16
#define C_   128
#define CHW_ 131072   // 128*32*32
#define NBLK 256      // persistent grid: 16 b x 16 rowpairs, 1 block/CU

__device__ __forceinline__ unsigned short f2bf(float f) {
  union { float f; unsigned int i; } v; v.f = f;
  unsigned int lsb = (v.i >> 16) & 1u;
  v.i += 0x7fffu + lsb;
  return (unsigned short)(v.i >> 16);
}

// ---- weight prep: W[O][I][3][3] f32 -> wpk[ks][co][ci&31] bf16, ks = off*4 + (ci>>5)
__global__ void prep_weights(const float* __restrict__ W1, const float* __restrict__ W2,
                             unsigned short* __restrict__ w1bf, unsigned short* __restrict__ w2bf) {
  int j = blockIdx.x * 256 + threadIdx.x;
  if (j >= 2 * 147456) return;
  int which = j / 147456;
  int r = j - which * 147456;
  int ks = r >> 12;
  int co = (r >> 5) & 127;
  int c5 = r & 31;
  int off = ks >> 2;
  int ci  = (ks & 3) * 32 + c5;
  const float* src = which ? W2 : W1;
  unsigned short* dst = which ? w2bf : w1bf;
  dst[r] = f2bf(src[(co * 128 + ci) * 9 + off]);
}

// ---- init: y32 = y0 (NCHW f32); dout[:,t=0,...] = y0
__global__ void init_copy(const float* __restrict__ y0, float* __restrict__ y32,
                          float* __restrict__ dout) {
  int i = blockIdx.x * 256 + threadIdx.x;
  if (i >= B_ * CHW_) return;
  float v = y0[i];
  y32[i] = v;
  int b = i >> 17, chw = i & (CHW_ - 1);
  dout[b * 25 * CHW_ + chw] = v;
}

// ---- init: tmp_bf (NHWC bf16) = transpose(y0)
__global__ void init_transpose(const float* __restrict__ y0, unsigned short* __restrict__ tmp_bf) {
  __shared__ float t[32][33];
  int blk = blockIdx.x;          // 16 b * 4 co-tiles * 32 pix-tiles = 2048
  int b = blk >> 7;
  int rem = blk & 127;
  int co0 = (rem >> 5) * 32;
  int p0  = (rem & 31) * 32;
  int tx = threadIdx.x & 31, ty = threadIdx.x >> 5;
  #pragma unroll
  for (int k = 0; k < 4; k++) {
    int cl = ty + k * 8;
    t[cl][tx] = y0[b * CHW_ + (co0 + cl) * 1024 + p0 + tx];
  }
  __syncthreads();
  #pragma unroll
  for (int k = 0; k < 4; k++) {
    int pl = ty + k * 8;
    tmp_bf[(b * 1024 + p0 + pl) * 128 + co0 + tx] = f2bf(t[tx][pl]);
  }
}

// ---- per-image barrier: 16 blocks, monotone arrival counter (no reset -> no
// reuse race under relaxed atomics). No device fences: only tmp crosses
// blocks, and it moves via agent-scope atomics (device-coherent via LLC),
// so L2-cached weights / y32 / acc32 are never invalidated.
__device__ __forceinline__ void gbar_img(unsigned* cnt, unsigned target) {
  asm volatile("s_waitcnt vmcnt(0)" ::: "memory");   // each wave drains its stores
  __syncthreads();
  if (threadIdx.x == 0) {
    __hip_atomic_fetch_add(cnt, 1u, __ATOMIC_RELAXED, __HIP_MEMORY_SCOPE_AGENT);
    int guard = 0;
    while (__hip_atomic_load(cnt, __ATOMIC_RELAXED, __HIP_MEMORY_SCOPE_AGENT) < target) {
      __builtin_amdgcn_s_sleep(2);
      if (++guard > 100000000) break;   // fail loudly, never hang
    }
  }
  __syncthreads();
  asm volatile("" ::: "memory");
}

__device__ __forceinline__ bf16x8 ld_coherent16(const unsigned short* p) {
  union { unsigned long long u[2]; bf16x8 v; } r;
  const unsigned long long* q = (const unsigned long long*)p;
  r.u[0] = __hip_atomic_load(q,     __ATOMIC_RELAXED, __HIP_MEMORY_SCOPE_AGENT);
  r.u[1] = __hip_atomic_load(q + 1, __ATOMIC_RELAXED, __HIP_MEMORY_SCOPE_AGENT);
  return r.v;
}

__device__ __forceinline__ void st_coherent8(unsigned short* p, u16x4 v) {
  union { u16x4 v; unsigned long long u; } r; r.v = v;
  __hip_atomic_store((unsigned long long*)p, r.u, __ATOMIC_RELAXED, __HIP_MEMORY_SCOPE_AGENT);
}

// ---- persistent fused ODE solver: 24 RK4 steps x 4 fused (conv1+conv2)
// phases; z lives only in LDS (1-row halo recomputed redundantly: conv1 on
// 4 rows instead of 2 -> 1.5x conv1 FLOPs, zero z global traffic, 96 barriers
// instead of 192).
// Block: 2 output rows x 128 co, 8 waves, 1 block/CU.
// conv1 wave: zrow (0..3) x cohalf: 64co x 32sp, acc[4][2].
// conv2 wave: row (0..1) x colhalf x cohalf: 64co x 16sp, acc[4].
__global__ __launch_bounds__(512, 2)
void ode_persistent(const unsigned short* __restrict__ w1bf,
                    const unsigned short* __restrict__ w2bf,
                    const float* __restrict__ b1v, const float* __restrict__ b2v,
                    unsigned short* __restrict__ tmp_bf,
                    float* __restrict__ y32, float* __restrict__ acc32,
                    float* __restrict__ dout, const float* __restrict__ tarr,
                    unsigned* __restrict__ bar)
{
  // IT: input tile, 6 rows (r0-2..r0+3) x 34 cols (-1..32) x 128 ci
  // ZT: z tile,     4 rows (r0-1..r0+2) x 34 cols (-1..32) x 128 co (LDS-only)
  __shared__ unsigned short IT[204 * 136];
  __shared__ unsigned short ZT[136 * 136];
  const int tid  = threadIdx.x;
  const int b    = blockIdx.x >> 4;
  const int r0   = (blockIdx.x & 15) * 2;
  const int lane = tid & 63;
  const int wave = tid >> 6;
  const int lhi  = lane >> 4;         // 0..3 (K octet / D row group)
  const int llo  = lane & 15;         // A: co row, B: sp col, D: col

  // conv1 wave mapping
  const int zr   = wave & 3;                    // z row idx (spatial r0-1+zr)
  const int ch1  = (wave >> 2) * 64;            // conv1 co base
  const bool live1 = (unsigned)(r0 - 1 + zr) < 32u;
  // conv2 wave mapping
  const int row_w = wave & 1;
  const int c0    = ((wave >> 1) & 1) * 16;
  const int ch2   = (wave >> 2) * 64;

  unsigned* const mycnt = bar + b * 64;   // per-image barrier line (256B apart)
  unsigned phase_no = 0;

  const unsigned short* a1base = w1bf + (ch1 + llo) * 32 + lhi * 8;
  const unsigned short* a2base = w2bf + (ch2 + llo) * 32 + lhi * 8;

  for (int step = 0; step < 24; ++step) {
    float t0 = tarr[step];
    float t1 = tarr[step + 1];
    // keep one operand in a VGPR: avoids V_ADD_F32 with two SGPR sources
    // (constant-bus violation -> backend compile error on gfx950)
    asm volatile("" : "+v"(t1));
    const float dt = t1 - t0;
    const float dt6 = dt * (1.f / 6.f), dt3 = dt * (1.f / 3.f), dth = dt * 0.5f;

    for (int st = 1; st <= 4; ++st) {
      // ---- stage tmp tile (6 rows, zero-padded halo) + zero ZT col pads
      for (int chunk = tid; chunk < 204 * 16 + 128; chunk += 512) {
        if (chunk < 204 * 16) {
          int pix = chunk >> 4;
          int oct = chunk & 15;
          int ir = pix / 34, ic = pix - ir * 34;
          int gr = r0 - 2 + ir, gc = ic - 1;
          bf16x8 v = {0, 0, 0, 0, 0, 0, 0, 0};
          if ((unsigned)gr < 32u && (unsigned)gc < 32u)
            v = ld_coherent16(tmp_bf + ((b * 32 + gr) * 32 + gc) * 128 + oct * 8);
          *(bf16x8*)(IT + pix * 136 + oct * 8) = v;
        } else {
          int padidx = chunk - 204 * 16;      // 0..127
          int zp  = padidx >> 4;              // 0..7 : 4 zrows x 2 sides
          int oct = padidx & 15;
          int zpix = (zp >> 1) * 34 + ((zp & 1) ? 33 : 0);
          bf16x8 z = {0, 0, 0, 0, 0, 0, 0, 0};
          *(bf16x8*)(ZT + zpix * 136 + oct * 8) = z;
        }
      }
      __syncthreads();

      // ---- conv1: z = tanh(conv(tmp,W1)+b1) for 4 rows -> ZT (LDS only)
      {
        f32x4 a1[4][2];
        #pragma unroll
        for (int i = 0; i < 4; i++) { a1[i][0] = (f32x4){0,0,0,0}; a1[i][1] = (f32x4){0,0,0,0}; }
        for (int off = 0; off < 9; ++off) {
          const int dh = off / 3;
          const int dw = off - 3 * dh;
          const int prow = (zr + dh) * 34 + llo + dw;
          #pragma unroll
          for (int kk = 0; kk < 4; ++kk) {
            const int ks = off * 4 + kk;
            bf16x8 afr[4], bfr[2];
            #pragma unroll
            for (int ct = 0; ct < 4; ++ct)
              afr[ct] = *(const bf16x8*)(a1base + ks * 4096 + ct * 512);
            bfr[0] = *(const bf16x8*)(IT + prow * 136 + kk * 32 + lhi * 8);
            bfr[1] = *(const bf16x8*)(IT + (prow + 16) * 136 + kk * 32 + lhi * 8);
            #pragma unroll
            for (int ct = 0; ct < 4; ++ct)
              #pragma unroll
              for (int spt = 0; spt < 2; ++spt)
                a1[ct][spt] = __builtin_amdgcn_mfma_f32_16x16x32_bf16(afr[ct], bfr[spt], a1[ct][spt], 0, 0, 0);
          }
        }
        #pragma unroll
        for (int ct = 0; ct < 4; ++ct) {
          const int co = ch1 + ct * 16 + lhi * 4;
          f32x4 bia = *(const f32x4*)(b1v + co);
          #pragma unroll
          for (int spt = 0; spt < 2; ++spt) {
            const int c = spt * 16 + llo;
            u16x4 pk;
            #pragma unroll
            for (int reg = 0; reg < 4; ++reg)
              pk[reg] = live1 ? f2bf(tanhf(a1[ct][spt][reg] + bia[reg])) : (unsigned short)0;
            *(u16x4*)(ZT + (zr * 34 + c + 1) * 136 + co) = pk;
          }
        }
      }
      __syncthreads();

      // ---- conv2: k = conv(z,W2)+b2 on own 2 rows + RK4 stage update
      {
        f32x4 a2[4];
        #pragma unroll
        for (int i = 0; i < 4; i++) a2[i] = (f32x4){0,0,0,0};
        for (int off = 0; off < 9; ++off) {
          const int dh = off / 3;
          const int dw = off - 3 * dh;
          const int zpix = (row_w + dh) * 34 + c0 + llo + dw;
          #pragma unroll
          for (int kk = 0; kk < 4; ++kk) {
            const int ks = off * 4 + kk;
            bf16x8 afr[4];
            #pragma unroll
            for (int ct = 0; ct < 4; ++ct)
              afr[ct] = *(const bf16x8*)(a2base + ks * 4096 + ct * 512);
            bf16x8 bfr = *(const bf16x8*)(ZT + zpix * 136 + kk * 32 + lhi * 8);
            #pragma unroll
            for (int ct = 0; ct < 4; ++ct)
              a2[ct] = __builtin_amdgcn_mfma_f32_16x16x32_bf16(afr[ct], bfr, a2[ct], 0, 0, 0);
          }
        }
        const int row = r0 + row_w;
        const int col = c0 + llo;
        #pragma unroll
        for (int ct = 0; ct < 4; ++ct) {
          const int co0 = ch2 + ct * 16 + lhi * 4;
          f32x4 bia = *(const f32x4*)(b2v + co0);
          const int pnhwc = (b * 1024 + row * 32 + col) * 128 + co0;
          const int idx0  = b * CHW_ + co0 * 1024 + row * 32 + col;
          u16x4 pk;
          #pragma unroll
          for (int reg = 0; reg < 4; ++reg) {
            float kv = a2[ct][reg] + bia[reg];
            int id = idx0 + reg * 1024;
            float tv;
            if (st == 1)      { float yv = y32[id]; acc32[id] = yv + dt6 * kv; tv = yv + dth * kv; }
            else if (st == 2) { float yv = y32[id]; acc32[id] += dt3 * kv;     tv = yv + dth * kv; }
            else if (st == 3) { float yv = y32[id]; acc32[id] += dt3 * kv;     tv = yv + dt * kv; }
            else {
              tv = acc32[id] + dt6 * kv;
              y32[id] = tv;
              dout[(b * 25 + step + 1) * CHW_ + co0 * 1024 + row * 32 + col + reg * 1024] = tv;
            }
            pk[reg] = f2bf(tv);
          }
          st_coherent8(tmp_bf + pnhwc, pk);
        }
      }

      ++phase_no;
      gbar_img(mycnt, phase_no * 16u);
    }
  }
}

extern "C" void kernel_launch(void* const* d_in, const int* in_sizes, int n_in,
                              void* d_out, int out_size, void* d_ws, size_t ws_size,
                              hipStream_t stream) {
  const float* y0   = (const float*)d_in[0];
  const float* tarr = (const float*)d_in[1];
  const float* W1   = (const float*)d_in[2];
  const float* b1   = (const float*)d_in[3];
  const float* W2   = (const float*)d_in[4];
  const float* b2   = (const float*)d_in[5];
  float* dout = (float*)d_out;

  char* ws = (char*)d_ws;
  float* y32             = (float*)(ws);                          // 8 MB
  float* acc32           = (float*)(ws + (8u << 20));             // 8 MB
  unsigned short* tmp_bf = (unsigned short*)(ws + (16u << 20));   // 4 MB (NHWC)
  unsigned short* w1bf   = (unsigned short*)(ws + (20u << 20));   // 288 KB
  unsigned short* w2bf   = (unsigned short*)(ws + (20u << 20) + 294912);
  unsigned* bar          = (unsigned*)(ws + (20u << 20) + 655360);

  prep_weights<<<(2 * 147456 + 255) / 256, 256, 0, stream>>>(W1, W2, w1bf, w2bf);
  init_copy<<<(B_ * CHW_ + 255) / 256, 256, 0, stream>>>(y0, y32, dout);
  init_transpose<<<2048, 256, 0, stream>>>(y0, tmp_bf);
  hipMemsetAsync(bar, 0, 16 * 256, stream);

  unsigned short* w1p = w1bf; unsigned short* w2p = w2bf;
  const float* b1p = b1; const float* b2p = b2;
  unsigned short* tp = tmp_bf;
  float* yp = y32; float* ap = acc32; float* dp = dout;
  const float* tap = tarr; unsigned* bp = bar;
  void* kargs[] = {&w1p, &w2p, &b1p, &b2p, &tp, &yp, &ap, &dp, &tap, &bp};
  hipError_t rc = hipLaunchCooperativeKernel((void*)ode_persistent, dim3(NBLK), dim3(512),
                                             kargs, 0, stream);
  if (rc != hipSuccess) {
    // fallback: plain launch. 1 block/CU (LDS 92KB) -> co-resident.
    ode_persistent<<<NBLK, 512, 0, stream>>>(w1p, w2p, b1p, b2p, tp, yp, ap, dp, tap, bp);
  }
}

// Round 8
// 3205.795 us; speedup vs baseline: 1.4372x; 1.4372x over previous
//
#include <hip/hip_runtime.h>
#include <hip/hip_bf16.h>
#include <math.h>

typedef __attribute__((ext_vector_type(8))) short bf16x8;
typedef __attribute__((ext_vector_type(4))) float f32x4;
typedef __attribute__((ext_vector_type(4))) unsigned short u16x4;

#define B_   16
#define C_   128
#define CHW_ 131072   // 128*32*32

__device__ __forceinline__ unsigned short f2bf(float f) {
  union { float f; unsigned int i; } v; v.f = f;
  unsigned int lsb = (v.i >> 16) & 1u;
  v.i += 0x7fffu + lsb;
  return (unsigned short)(v.i >> 16);
}

// ---- weight prep: W[O][I][3][3] f32 -> wpk[ks][co][ci&31] bf16, ks = off*4 + (ci>>5)
__global__ void prep_weights(const float* __restrict__ W1, const float* __restrict__ W2,
                             unsigned short* __restrict__ w1bf, unsigned short* __restrict__ w2bf) {
  int j = blockIdx.x * 256 + threadIdx.x;
  if (j >= 2 * 147456) return;
  int which = j / 147456;
  int r = j - which * 147456;
  int ks = r >> 12;
  int co = (r >> 5) & 127;
  int c5 = r & 31;
  int off = ks >> 2;
  int ci  = (ks & 3) * 32 + c5;
  const float* src = which ? W2 : W1;
  unsigned short* dst = which ? w2bf : w1bf;
  dst[r] = f2bf(src[(co * 128 + ci) * 9 + off]);
}

// ---- init: y32 = y0 (NCHW f32); dout[:,t=0,...] = y0
__global__ void init_copy(const float* __restrict__ y0, float* __restrict__ y32,
                          float* __restrict__ dout) {
  int i = blockIdx.x * 256 + threadIdx.x;
  if (i >= B_ * CHW_) return;
  float v = y0[i];
  y32[i] = v;
  int b = i >> 17, chw = i & (CHW_ - 1);
  dout[b * 25 * CHW_ + chw] = v;
}

// ---- init: tmp_bf (NHWC bf16) = transpose(y0)
__global__ void init_transpose(const float* __restrict__ y0, unsigned short* __restrict__ tmp_bf) {
  __shared__ float t[32][33];
  int blk = blockIdx.x;          // 16 b * 4 co-tiles * 32 pix-tiles = 2048
  int b = blk >> 7;
  int rem = blk & 127;
  int co0 = (rem >> 5) * 32;
  int p0  = (rem & 31) * 32;
  int tx = threadIdx.x & 31, ty = threadIdx.x >> 5;
  #pragma unroll
  for (int k = 0; k < 4; k++) {
    int cl = ty + k * 8;
    t[cl][tx] = y0[b * CHW_ + (co0 + cl) * 1024 + p0 + tx];
  }
  __syncthreads();
  #pragma unroll
  for (int k = 0; k < 4; k++) {
    int pl = ty + k * 8;
    tmp_bf[(b * 1024 + p0 + pl) * 128 + co0 + tx] = f2bf(t[tx][pl]);
  }
}

// ---- fused conv (+bias) kernel, implicit GEMM via MFMA 16x16x32 bf16.
// Block: 1 output row x 128 co, 256 thr. Grid: 16 b x 32 rows = 512 blocks
// (b = blockIdx>>5 so the 2 blocks co-resident on a CU are different images
// -> independent work overlaps: stage of one hides compute of the other).
// Wave (4/block): 32co x 32sp, acc[2][2]. Per K-step: 2 A-frags (L2) +
// 2 B-frags (LDS) -> 4 MFMA (each operand reused 2x).
// STAGE 0: out_bf = tanh(conv(in, W1)+b1)           (the z buffer)
// STAGE 1: k1 = conv+b2; acc = y + dt/6 k1; tmp = y + dt/2 k1
// STAGE 2: k2;           acc += dt/3 k2;   tmp = y + dt/2 k2
// STAGE 3: k3;           acc += dt/3 k3;   tmp = y + dt   k3
// STAGE 4: k4; ynew = acc + dt/6 k4 -> y32, d_out[:,t], tmp
template<int STAGE>
__global__ __launch_bounds__(256, 2)
void conv_kernel(const unsigned short* __restrict__ in_bf,   // NHWC bf16
                 const unsigned short* __restrict__ wpk,     // [36][128][32] bf16
                 const float* __restrict__ bias,             // [128]
                 unsigned short* __restrict__ out_bf,        // NHWC bf16
                 float* __restrict__ y32,                    // NCHW f32
                 float* __restrict__ acc32,                  // NCHW f32
                 float* __restrict__ dout,                   // [B][25][C][H][W]
                 const float* __restrict__ tarr, int step)
{
  // input tile: 3 rows (r0-1..r0+1) x 34 cols (-1..32) x 128 ci, row stride 136
  __shared__ unsigned short tile[102 * 136];
  const int tid = threadIdx.x;
  const int b   = blockIdx.x >> 5;
  const int r0  = blockIdx.x & 31;

  // stage input tile (zero-padded halo), 16B chunks, fully coalesced
  for (int chunk = tid; chunk < 102 * 16; chunk += 256) {
    int pix = chunk >> 4;
    int oct = chunk & 15;
    int tr = pix / 34, tc = pix - tr * 34;
    int gr = r0 - 1 + tr, gc = tc - 1;
    bf16x8 v = {0, 0, 0, 0, 0, 0, 0, 0};
    if ((unsigned)gr < 32u && (unsigned)gc < 32u)
      v = *(const bf16x8*)(in_bf + ((b * 32 + gr) * 32 + gc) * 128 + oct * 8);
    *(bf16x8*)(tile + pix * 136 + oct * 8) = v;
  }
  __syncthreads();

  const int lane = tid & 63;
  const int wave = tid >> 6;
  const int lhi = lane >> 4;     // 0..3  (K octet / D row group)
  const int llo = lane & 15;     // A: co row, B: sp col, D: col
  const int co_w = wave * 32;    // 32-co band per wave

  f32x4 acc[2][2];
  #pragma unroll
  for (int i = 0; i < 2; i++)
    #pragma unroll
    for (int j = 0; j < 2; j++)
      acc[i][j] = (f32x4){0.f, 0.f, 0.f, 0.f};

  // A: wpk[(ks*128 + co_w + ct*16 + llo)*32 + lhi*8]
  const unsigned short* abase = wpk + (co_w + llo) * 32 + lhi * 8;

  for (int off = 0; off < 9; ++off) {
    const int dh = off / 3;
    const int dw = off - 3 * dh;
    const int pixb = dh * 34 + llo + dw;
    #pragma unroll
    for (int kk = 0; kk < 4; ++kk) {
      const int ks = off * 4 + kk;           // K step (32 wide)
      bf16x8 afr[2], bfr[2];
      afr[0] = *(const bf16x8*)(abase + ks * 4096);
      afr[1] = *(const bf16x8*)(abase + ks * 4096 + 512);
      bfr[0] = *(const bf16x8*)(tile + pixb * 136 + kk * 32 + lhi * 8);
      bfr[1] = *(const bf16x8*)(tile + (pixb + 16) * 136 + kk * 32 + lhi * 8);
      #pragma unroll
      for (int ct = 0; ct < 2; ++ct)
        #pragma unroll
        for (int spt = 0; spt < 2; ++spt)
          acc[ct][spt] = __builtin_amdgcn_mfma_f32_16x16x32_bf16(afr[ct], bfr[spt], acc[ct][spt], 0, 0, 0);
    }
  }

  float dt = 0.f;
  if constexpr (STAGE >= 1) {
    float t0 = tarr[step];
    float t1 = tarr[step + 1];
    // keep one operand in a VGPR: avoids V_ADD_F32 with two SGPR sources
    // (constant-bus violation -> backend compile error on gfx950)
    asm volatile("" : "+v"(t1));
    dt = t1 - t0;
  }
  const float dt6 = dt * (1.f / 6.f), dt3 = dt * (1.f / 3.f), dth = dt * 0.5f;

  #pragma unroll
  for (int ct = 0; ct < 2; ++ct) {
    const int co0 = co_w + ct * 16 + lhi * 4;
    f32x4 bia = *(const f32x4*)(bias + co0);
    #pragma unroll
    for (int spt = 0; spt < 2; ++spt) {
      const int col = spt * 16 + llo;
      const int pnhwc = (b * 1024 + r0 * 32 + col) * 128 + co0;
      f32x4 a = acc[ct][spt];
      u16x4 pk;
      if constexpr (STAGE == 0) {
        #pragma unroll
        for (int reg = 0; reg < 4; ++reg) {
          float v = tanhf(a[reg] + bia[reg]);
          pk[reg] = f2bf(v);
        }
        *(u16x4*)(out_bf + pnhwc) = pk;
      } else {
        const int idx0 = b * CHW_ + co0 * 1024 + r0 * 32 + col;
        #pragma unroll
        for (int reg = 0; reg < 4; ++reg) {
          float kv = a[reg] + bia[reg];
          int id = idx0 + reg * 1024;
          float tv;
          if constexpr (STAGE == 1) {
            float yv = y32[id];
            acc32[id] = yv + dt6 * kv;
            tv = yv + dth * kv;
          } else if constexpr (STAGE == 2) {
            float yv = y32[id];
            acc32[id] += dt3 * kv;
            tv = yv + dth * kv;
          } else if constexpr (STAGE == 3) {
            float yv = y32[id];
            acc32[id] += dt3 * kv;
            tv = yv + dt * kv;
          } else {  // STAGE 4
            tv = acc32[id] + dt6 * kv;
            y32[id] = tv;
            dout[(b * 25 + step + 1) * CHW_ + co0 * 1024 + r0 * 32 + col + reg * 1024] = tv;
          }
          pk[reg] = f2bf(tv);
        }
        *(u16x4*)(out_bf + pnhwc) = pk;
      }
    }
  }
}

extern "C" void kernel_launch(void* const* d_in, const int* in_sizes, int n_in,
                              void* d_out, int out_size, void* d_ws, size_t ws_size,
                              hipStream_t stream) {
  const float* y0   = (const float*)d_in[0];
  const float* tarr = (const float*)d_in[1];
  const float* W1   = (const float*)d_in[2];
  const float* b1   = (const float*)d_in[3];
  const float* W2   = (const float*)d_in[4];
  const float* b2   = (const float*)d_in[5];
  float* dout = (float*)d_out;

  char* ws = (char*)d_ws;
  float* y32             = (float*)(ws);                          // 8 MB
  float* acc32           = (float*)(ws + (8u << 20));             // 8 MB
  unsigned short* tmp_bf = (unsigned short*)(ws + (16u << 20));   // 4 MB (NHWC)
  unsigned short* z_bf   = (unsigned short*)(ws + (20u << 20));   // 4 MB (NHWC)
  unsigned short* w1bf   = (unsigned short*)(ws + (24u << 20));   // 288 KB
  unsigned short* w2bf   = (unsigned short*)(ws + (24u << 20) + 294912);

  prep_weights<<<(2 * 147456 + 255) / 256, 256, 0, stream>>>(W1, W2, w1bf, w2bf);
  init_copy<<<(B_ * CHW_ + 255) / 256, 256, 0, stream>>>(y0, y32, dout);
  init_transpose<<<2048, 256, 0, stream>>>(y0, tmp_bf);

  for (int step = 0; step < 24; ++step) {
    conv_kernel<0><<<512, 256, 0, stream>>>(tmp_bf, w1bf, b1, z_bf, nullptr, nullptr, nullptr, tarr, step);
    conv_kernel<1><<<512, 256, 0, stream>>>(z_bf, w2bf, b2, tmp_bf, y32, acc32, dout, tarr, step);
    conv_kernel<0><<<512, 256, 0, stream>>>(tmp_bf, w1bf, b1, z_bf, nullptr, nullptr, nullptr, tarr, step);
    conv_kernel<2><<<512, 256, 0, stream>>>(z_bf, w2bf, b2, tmp_bf, y32, acc32, dout, tarr, step);
    conv_kernel<0><<<512, 256, 0, stream>>>(tmp_bf, w1bf, b1, z_bf, nullptr, nullptr, nullptr, tarr, step);
    conv_kernel<3><<<512, 256, 0, stream>>>(z_bf, w2bf, b2, tmp_bf, y32, acc32, dout, tarr, step);
    conv_kernel<0><<<512, 256, 0, stream>>>(tmp_bf, w1bf, b1, z_bf, nullptr, nullptr, nullptr, tarr, step);
    conv_kernel<4><<<512, 256, 0, stream>>>(z_bf, w2bf, b2, tmp_bf, y32, acc32, dout, tarr, step);
  }
}

// Round 9
// 2837.732 us; speedup vs baseline: 1.6236x; 1.1297x over previous
//
#include <hip/hip_runtime.h>
#include <hip/hip_bf16.h>
#include <math.h>

typedef __attribute__((ext_vector_type(8))) short bf16x8;
typedef __attribute__((ext_vector_type(4))) float f32x4;
typedef __attribute__((ext_vector_type(4))) unsigned short u16x4;

#define B_   16
#define C_   128
#define CHW_ 131072   // 128*32*32

__device__ __forceinline__ unsigned short f2bf(float f) {
  union { float f; unsigned int i; } v; v.f = f;
  unsigned int lsb = (v.i >> 16) & 1u;
  v.i += 0x7fffu + lsb;
  return (unsigned short)(v.i >> 16);
}

// ---- weight prep: W[O][I][3][3] f32 -> wpk[ks][co][ci&31] bf16, ks = off*4 + (ci>>5)
__global__ void prep_weights(const float* __restrict__ W1, const float* __restrict__ W2,
                             unsigned short* __restrict__ w1bf, unsigned short* __restrict__ w2bf) {
  int j = blockIdx.x * 256 + threadIdx.x;
  if (j >= 2 * 147456) return;
  int which = j / 147456;
  int r = j - which * 147456;
  int ks = r >> 12;
  int co = (r >> 5) & 127;
  int c5 = r & 31;
  int off = ks >> 2;
  int ci  = (ks & 3) * 32 + c5;
  const float* src = which ? W2 : W1;
  unsigned short* dst = which ? w2bf : w1bf;
  dst[r] = f2bf(src[(co * 128 + ci) * 9 + off]);
}

// ---- init: y32 = y0 (NCHW f32); dout[:,t=0,...] = y0
__global__ void init_copy(const float* __restrict__ y0, float* __restrict__ y32,
                          float* __restrict__ dout) {
  int i = blockIdx.x * 256 + threadIdx.x;
  if (i >= B_ * CHW_) return;
  float v = y0[i];
  y32[i] = v;
  int b = i >> 17, chw = i & (CHW_ - 1);
  dout[b * 25 * CHW_ + chw] = v;
}

// ---- init: tmp_bf (NHWC bf16) = transpose(y0)
__global__ void init_transpose(const float* __restrict__ y0, unsigned short* __restrict__ tmp_bf) {
  __shared__ float t[32][33];
  int blk = blockIdx.x;          // 16 b * 4 co-tiles * 32 pix-tiles = 2048
  int b = blk >> 7;
  int rem = blk & 127;
  int co0 = (rem >> 5) * 32;
  int p0  = (rem & 31) * 32;
  int tx = threadIdx.x & 31, ty = threadIdx.x >> 5;
  #pragma unroll
  for (int k = 0; k < 4; k++) {
    int cl = ty + k * 8;
    t[cl][tx] = y0[b * CHW_ + (co0 + cl) * 1024 + p0 + tx];
  }
  __syncthreads();
  #pragma unroll
  for (int k = 0; k < 4; k++) {
    int pl = ty + k * 8;
    tmp_bf[(b * 1024 + p0 + pl) * 128 + co0 + tx] = f2bf(t[tx][pl]);
  }
}

// ---- fused RK4 stage kernel (multi-launch, plain cached loads).
// One launch = one RK4 stage: z = tanh(conv1(tmp)+b1) computed into LDS with
// a 1-row halo (conv1 on 4 z-rows for a 2-row output tile -> no z global
// round-trip, no device barrier), then k = conv2(z)+b2 + RK4 update.
// Grid: 16 images x 16 rowpairs = 256 blocks (1/CU), 512 thr (8 waves).
// conv1 wave: ch32 x zrow-pair x 32sp, acc[2][2][2]: per K-step 2 A-loads(L2)
//   + 4 B-reads(LDS) -> 8 MFMA.
// conv2 wave: ch32 x row x 32sp, acc[2][2]: 2 A + 2 B -> 4 MFMA.
// ST 1: k1: acc=y+dt/6 k1; tmp=y+dt/2 k1
// ST 2: k2: acc+=dt/3 k2;  tmp=y+dt/2 k2
// ST 3: k3: acc+=dt/3 k3;  tmp=y+dt k3
// ST 4: k4: ynew=acc+dt/6 k4 -> y32, dout[:,step+1], tmp
template<int ST>
__global__ __launch_bounds__(512, 2)
void fused_stage(const unsigned short* __restrict__ w1bf,
                 const unsigned short* __restrict__ w2bf,
                 const float* __restrict__ b1v, const float* __restrict__ b2v,
                 unsigned short* __restrict__ tmp_bf,
                 float* __restrict__ y32, float* __restrict__ acc32,
                 float* __restrict__ dout, const float* __restrict__ tarr, int step)
{
  // IT: tmp tile, 6 rows (r0-2..r0+3) x 34 cols x 128 ci, row-pixel stride 136
  // ZT: z tile,   4 rows (r0-1..r0+2) x 34 cols x 128 co (LDS-only)
  __shared__ unsigned short IT[204 * 136];
  __shared__ unsigned short ZT[136 * 136];
  const int tid  = threadIdx.x;
  const int b    = blockIdx.x >> 4;
  const int r0   = (blockIdx.x & 15) * 2;
  const int lane = tid & 63;
  const int wave = tid >> 6;
  const int lhi  = lane >> 4;         // 0..3 (K octet / D row group)
  const int llo  = lane & 15;         // A: co row, B: sp col, D: col

  // conv1 wave mapping: ch-band (32 co) x zrow-pair
  const int ch1  = (wave & 3) * 32;
  const int zrp  = (wave >> 2) * 2;           // zr base (0 or 2)
  // conv2 wave mapping: ch-band (32 co) x output row
  const int row_w = wave & 1;
  const int ch2   = (wave >> 1) * 32;

  const unsigned short* a1base = w1bf + (ch1 + llo) * 32 + lhi * 8;
  const unsigned short* a2base = w2bf + (ch2 + llo) * 32 + lhi * 8;

  float t0 = tarr[step];
  float t1 = tarr[step + 1];
  // keep one operand in a VGPR: avoids V_ADD_F32 with two SGPR sources
  // (constant-bus violation -> backend compile error on gfx950)
  asm volatile("" : "+v"(t1));
  const float dt = t1 - t0;
  const float dt6 = dt * (1.f / 6.f), dt3 = dt * (1.f / 3.f), dth = dt * 0.5f;

  // ---- stage tmp tile (6 rows, zero-padded halo) + zero ZT col pads
  for (int chunk = tid; chunk < 204 * 16 + 128; chunk += 512) {
    if (chunk < 204 * 16) {
      int pix = chunk >> 4;
      int oct = chunk & 15;
      int ir = pix / 34, ic = pix - ir * 34;
      int gr = r0 - 2 + ir, gc = ic - 1;
      bf16x8 v = {0, 0, 0, 0, 0, 0, 0, 0};
      if ((unsigned)gr < 32u && (unsigned)gc < 32u)
        v = *(const bf16x8*)(tmp_bf + ((b * 32 + gr) * 32 + gc) * 128 + oct * 8);
      *(bf16x8*)(IT + pix * 136 + oct * 8) = v;
    } else {
      int padidx = chunk - 204 * 16;      // 0..127 : 4 zrows x 2 sides x 16 oct
      int zp  = padidx >> 4;
      int oct = padidx & 15;
      int zpix = (zp >> 1) * 34 + ((zp & 1) ? 33 : 0);
      bf16x8 z = {0, 0, 0, 0, 0, 0, 0, 0};
      *(bf16x8*)(ZT + zpix * 136 + oct * 8) = z;
    }
  }
  __syncthreads();

  // ---- conv1: z = tanh(conv(tmp,W1)+b1) for zrows zrp..zrp+1 -> ZT
  {
    f32x4 a1[2][2][2];   // [ct][q][spt]
    #pragma unroll
    for (int i = 0; i < 2; i++)
      #pragma unroll
      for (int j = 0; j < 2; j++) {
        a1[i][j][0] = (f32x4){0, 0, 0, 0};
        a1[i][j][1] = (f32x4){0, 0, 0, 0};
      }
    for (int off = 0; off < 9; ++off) {
      const int dh = off / 3;
      const int dw = off - 3 * dh;
      #pragma unroll
      for (int kk = 0; kk < 4; ++kk) {
        const int ks = off * 4 + kk;
        bf16x8 afr[2], bfr[2][2];
        afr[0] = *(const bf16x8*)(a1base + ks * 4096);
        afr[1] = *(const bf16x8*)(a1base + ks * 4096 + 512);
        #pragma unroll
        for (int q = 0; q < 2; ++q) {
          const int prow = (zrp + q + dh) * 34 + llo + dw;
          bfr[q][0] = *(const bf16x8*)(IT + prow * 136 + kk * 32 + lhi * 8);
          bfr[q][1] = *(const bf16x8*)(IT + (prow + 16) * 136 + kk * 32 + lhi * 8);
        }
        #pragma unroll
        for (int ct = 0; ct < 2; ++ct)
          #pragma unroll
          for (int q = 0; q < 2; ++q)
            #pragma unroll
            for (int spt = 0; spt < 2; ++spt)
              a1[ct][q][spt] = __builtin_amdgcn_mfma_f32_16x16x32_bf16(afr[ct], bfr[q][spt], a1[ct][q][spt], 0, 0, 0);
      }
    }
    #pragma unroll
    for (int ct = 0; ct < 2; ++ct) {
      const int co = ch1 + ct * 16 + lhi * 4;
      f32x4 bia = *(const f32x4*)(b1v + co);
      #pragma unroll
      for (int q = 0; q < 2; ++q) {
        const int zr = zrp + q;
        const bool live = (unsigned)(r0 - 1 + zr) < 32u;
        #pragma unroll
        for (int spt = 0; spt < 2; ++spt) {
          const int c = spt * 16 + llo;
          u16x4 pk;
          #pragma unroll
          for (int reg = 0; reg < 4; ++reg)
            pk[reg] = live ? f2bf(tanhf(a1[ct][q][spt][reg] + bia[reg])) : (unsigned short)0;
          *(u16x4*)(ZT + (zr * 34 + c + 1) * 136 + co) = pk;
        }
      }
    }
  }
  __syncthreads();

  // ---- conv2: k = conv(z,W2)+b2 on own row + RK4 stage update
  {
    f32x4 a2[2][2];
    #pragma unroll
    for (int i = 0; i < 2; i++) { a2[i][0] = (f32x4){0,0,0,0}; a2[i][1] = (f32x4){0,0,0,0}; }
    for (int off = 0; off < 9; ++off) {
      const int dh = off / 3;
      const int dw = off - 3 * dh;
      const int prow = (row_w + dh) * 34 + llo + dw;
      #pragma unroll
      for (int kk = 0; kk < 4; ++kk) {
        const int ks = off * 4 + kk;
        bf16x8 afr[2], bfr[2];
        afr[0] = *(const bf16x8*)(a2base + ks * 4096);
        afr[1] = *(const bf16x8*)(a2base + ks * 4096 + 512);
        bfr[0] = *(const bf16x8*)(ZT + prow * 136 + kk * 32 + lhi * 8);
        bfr[1] = *(const bf16x8*)(ZT + (prow + 16) * 136 + kk * 32 + lhi * 8);
        #pragma unroll
        for (int ct = 0; ct < 2; ++ct)
          #pragma unroll
          for (int spt = 0; spt < 2; ++spt)
            a2[ct][spt] = __builtin_amdgcn_mfma_f32_16x16x32_bf16(afr[ct], bfr[spt], a2[ct][spt], 0, 0, 0);
      }
    }
    const int row = r0 + row_w;
    #pragma unroll
    for (int ct = 0; ct < 2; ++ct) {
      const int co0 = ch2 + ct * 16 + lhi * 4;
      f32x4 bia = *(const f32x4*)(b2v + co0);
      #pragma unroll
      for (int spt = 0; spt < 2; ++spt) {
        const int col = spt * 16 + llo;
        const int pnhwc = (b * 1024 + row * 32 + col) * 128 + co0;
        const int idx0  = b * CHW_ + co0 * 1024 + row * 32 + col;
        u16x4 pk;
        #pragma unroll
        for (int reg = 0; reg < 4; ++reg) {
          float kv = a2[ct][spt][reg] + bia[reg];
          int id = idx0 + reg * 1024;
          float tv;
          if constexpr (ST == 1)      { float yv = y32[id]; acc32[id] = yv + dt6 * kv; tv = yv + dth * kv; }
          else if constexpr (ST == 2) { float yv = y32[id]; acc32[id] += dt3 * kv;     tv = yv + dth * kv; }
          else if constexpr (ST == 3) { float yv = y32[id]; acc32[id] += dt3 * kv;     tv = yv + dt * kv; }
          else {
            tv = acc32[id] + dt6 * kv;
            y32[id] = tv;
            dout[(b * 25 + step + 1) * CHW_ + co0 * 1024 + row * 32 + col + reg * 1024] = tv;
          }
          pk[reg] = f2bf(tv);
        }
        *(u16x4*)(tmp_bf + pnhwc) = pk;
      }
    }
  }
}

extern "C" void kernel_launch(void* const* d_in, const int* in_sizes, int n_in,
                              void* d_out, int out_size, void* d_ws, size_t ws_size,
                              hipStream_t stream) {
  const float* y0   = (const float*)d_in[0];
  const float* tarr = (const float*)d_in[1];
  const float* W1   = (const float*)d_in[2];
  const float* b1   = (const float*)d_in[3];
  const float* W2   = (const float*)d_in[4];
  const float* b2   = (const float*)d_in[5];
  float* dout = (float*)d_out;

  char* ws = (char*)d_ws;
  float* y32             = (float*)(ws);                          // 8 MB
  float* acc32           = (float*)(ws + (8u << 20));             // 8 MB
  unsigned short* tmp_bf = (unsigned short*)(ws + (16u << 20));   // 4 MB (NHWC)
  unsigned short* w1bf   = (unsigned short*)(ws + (20u << 20));   // 288 KB
  unsigned short* w2bf   = (unsigned short*)(ws + (20u << 20) + 294912);

  prep_weights<<<(2 * 147456 + 255) / 256, 256, 0, stream>>>(W1, W2, w1bf, w2bf);
  init_copy<<<(B_ * CHW_ + 255) / 256, 256, 0, stream>>>(y0, y32, dout);
  init_transpose<<<2048, 256, 0, stream>>>(y0, tmp_bf);

  for (int step = 0; step < 24; ++step) {
    fused_stage<1><<<256, 512, 0, stream>>>(w1bf, w2bf, b1, b2, tmp_bf, y32, acc32, dout, tarr, step);
    fused_stage<2><<<256, 512, 0, stream>>>(w1bf, w2bf, b1, b2, tmp_bf, y32, acc32, dout, tarr, step);
    fused_stage<3><<<256, 512, 0, stream>>>(w1bf, w2bf, b1, b2, tmp_bf, y32, acc32, dout, tarr, step);
    fused_stage<4><<<256, 512, 0, stream>>>(w1bf, w2bf, b1, b2, tmp_bf, y32, acc32, dout, tarr, step);
  }
}